// Round 1
// baseline (116.540 us; speedup 1.0000x reference)
//
#include <hip/hip_runtime.h>

#define NB 128      // batch
#define NT 4096     // T
#define DKD 16      // d_k == d_q
#define DW 32       // d_w
#define CHUNKS 4    // T split into chunks for occupancy
#define TC 1024     // NT / CHUNKS
#define BLK 256
#define PT 4        // t-values per thread: TC / BLK

__device__ __forceinline__ float fast_tanh(float x) {
    // tanh(x) = 1 - 2/(e^{2x}+1); exact at +/-inf limits, ~1 ulp rcp error.
    float e = __expf(2.0f * x);
    return 1.0f - 2.0f * __builtin_amdgcn_rcpf(e + 1.0f);
}

// Kernel 1: per (batch, chunk) block. Computes scores, p = exp(score)
// (no max-subtract needed: |score| <= ||v_w||_1 + |v_b| ~ 2.6 since tanh is
// bounded), writes unnormalized p to the attn output region, and reduces
// per-chunk l = sum(p) and ctx[d] = sum(p * value[d]) into workspace.
__global__ __launch_bounds__(BLK) void aa_score(
    const float* __restrict__ query, const float* __restrict__ key,
    const float* __restrict__ value, const float* __restrict__ W1,
    const float* __restrict__ W2, const float* __restrict__ bias,
    const float* __restrict__ v_w, const float* __restrict__ v_b,
    float* __restrict__ attn,      // d_out + 2048, unnormalized p written here
    float* __restrict__ ws_l,      // [NB*CHUNKS]
    float* __restrict__ ws_ctx)    // [NB*CHUNKS*16]
{
    const int b   = blockIdx.x / CHUNKS;
    const int c   = blockIdx.x % CHUNKS;
    const int tid = threadIdx.x;

    __shared__ float s_w2[DW * DKD];   // [w][d] row-major
    __shared__ float s_comb[DW];       // q_proj[w] + bias (block-uniform)
    __shared__ float s_vw[DW];
    __shared__ float s_rctx[4 * 16];   // per-wave partial ctx
    __shared__ float s_rl[4];

    // Preamble: stage W2 (128 float4) and compute q_proj + bias (32 lanes).
    if (tid < 128)
        reinterpret_cast<float4*>(s_w2)[tid] = reinterpret_cast<const float4*>(W2)[tid];
    if (tid >= 128 && tid < 128 + DW) {
        const int w = tid - 128;
        float acc = bias[0];
        const float* q  = query + b * DKD;
        const float* w1 = W1 + w * DKD;
        #pragma unroll
        for (int d = 0; d < DKD; ++d) acc = fmaf(q[d], w1[d], acc);
        s_comb[w] = acc;
        s_vw[w]   = v_w[w];
    }
    __syncthreads();

    const float vb = v_b[0];
    // Thread handles PT consecutive t's: 256 B contiguous per lane, coalesced.
    const size_t tbase = (size_t)b * NT + (size_t)c * TC + (size_t)tid * PT;
    const float4* kp = reinterpret_cast<const float4*>(key)   + tbase * 4;
    const float4* vp = reinterpret_cast<const float4*>(value) + tbase * 4;

    float4 k0[PT], k1[PT], k2[PT], k3[PT];
    #pragma unroll
    for (int j = 0; j < PT; ++j) {
        k0[j] = kp[4*j + 0]; k1[j] = kp[4*j + 1];
        k2[j] = kp[4*j + 2]; k3[j] = kp[4*j + 3];
    }

    float sc[PT];
    #pragma unroll
    for (int j = 0; j < PT; ++j) sc[j] = vb;

    // w-outer, t-inner: each W2 row read from LDS once per PT t's
    // (4 ds_read_b128 per w) -> LDS pipe stays well under the FMA pipe.
    #pragma unroll 4
    for (int w = 0; w < DW; ++w) {
        const float4* wr = reinterpret_cast<const float4*>(s_w2 + w * DKD);
        const float4 w0 = wr[0], w1 = wr[1], w2 = wr[2], w3 = wr[3];
        const float cw = s_comb[w];
        const float vw = s_vw[w];
        #pragma unroll
        for (int j = 0; j < PT; ++j) {
            float h = cw;
            h = fmaf(k0[j].x, w0.x, h); h = fmaf(k0[j].y, w0.y, h);
            h = fmaf(k0[j].z, w0.z, h); h = fmaf(k0[j].w, w0.w, h);
            h = fmaf(k1[j].x, w1.x, h); h = fmaf(k1[j].y, w1.y, h);
            h = fmaf(k1[j].z, w1.z, h); h = fmaf(k1[j].w, w1.w, h);
            h = fmaf(k2[j].x, w2.x, h); h = fmaf(k2[j].y, w2.y, h);
            h = fmaf(k2[j].z, w2.z, h); h = fmaf(k2[j].w, w2.w, h);
            h = fmaf(k3[j].x, w3.x, h); h = fmaf(k3[j].y, w3.y, h);
            h = fmaf(k3[j].z, w3.z, h); h = fmaf(k3[j].w, w3.w, h);
            sc[j] = fmaf(fast_tanh(h), vw, sc[j]);
        }
    }

    // p = exp(score); accumulate l and ctx; write unnormalized p.
    float l = 0.0f;
    float ctx[16];
    #pragma unroll
    for (int d = 0; d < 16; ++d) ctx[d] = 0.0f;

    float p[PT];
    #pragma unroll
    for (int j = 0; j < PT; ++j) {
        p[j] = __expf(sc[j]);
        l += p[j];
        const float4 v0 = vp[4*j + 0], v1 = vp[4*j + 1];
        const float4 v2 = vp[4*j + 2], v3 = vp[4*j + 3];
        ctx[ 0] = fmaf(p[j], v0.x, ctx[ 0]); ctx[ 1] = fmaf(p[j], v0.y, ctx[ 1]);
        ctx[ 2] = fmaf(p[j], v0.z, ctx[ 2]); ctx[ 3] = fmaf(p[j], v0.w, ctx[ 3]);
        ctx[ 4] = fmaf(p[j], v1.x, ctx[ 4]); ctx[ 5] = fmaf(p[j], v1.y, ctx[ 5]);
        ctx[ 6] = fmaf(p[j], v1.z, ctx[ 6]); ctx[ 7] = fmaf(p[j], v1.w, ctx[ 7]);
        ctx[ 8] = fmaf(p[j], v2.x, ctx[ 8]); ctx[ 9] = fmaf(p[j], v2.y, ctx[ 9]);
        ctx[10] = fmaf(p[j], v2.z, ctx[10]); ctx[11] = fmaf(p[j], v2.w, ctx[11]);
        ctx[12] = fmaf(p[j], v3.x, ctx[12]); ctx[13] = fmaf(p[j], v3.y, ctx[13]);
        ctx[14] = fmaf(p[j], v3.z, ctx[14]); ctx[15] = fmaf(p[j], v3.w, ctx[15]);
    }
    reinterpret_cast<float4*>(attn + (size_t)b * NT + (size_t)c * TC)[tid] =
        make_float4(p[0], p[1], p[2], p[3]);

    // Block reduction: wave shuffle-reduce, then 4 waves via LDS.
    #pragma unroll
    for (int o = 32; o > 0; o >>= 1) l += __shfl_xor(l, o);
    #pragma unroll
    for (int d = 0; d < 16; ++d) {
        #pragma unroll
        for (int o = 32; o > 0; o >>= 1) ctx[d] += __shfl_xor(ctx[d], o);
    }
    const int wave = tid >> 6;
    const int lane = tid & 63;
    if (lane == 0) {
        s_rl[wave] = l;
        #pragma unroll
        for (int d = 0; d < 16; ++d) s_rctx[wave * 16 + d] = ctx[d];
    }
    __syncthreads();
    const int slot = b * CHUNKS + c;
    if (tid < 16)
        ws_ctx[slot * 16 + tid] =
            s_rctx[tid] + s_rctx[16 + tid] + s_rctx[32 + tid] + s_rctx[48 + tid];
    if (tid == 0)
        ws_l[slot] = s_rl[0] + s_rl[1] + s_rl[2] + s_rl[3];
}

// Kernel 2: normalize attn in place by 1/L (L = sum of chunk l's) and write
// context = (sum of chunk ctx's) / L. Each block recomputes L redundantly
// from 4 broadcast loads — avoids a third kernel.
__global__ __launch_bounds__(BLK) void aa_finish(
    float* __restrict__ out,          // [0,2048) context, [2048,...) attn
    const float* __restrict__ ws_l,
    const float* __restrict__ ws_ctx)
{
    const int b   = blockIdx.x / CHUNKS;
    const int c   = blockIdx.x % CHUNKS;
    const int tid = threadIdx.x;
    const float L = ws_l[b*CHUNKS + 0] + ws_l[b*CHUNKS + 1] +
                    ws_l[b*CHUNKS + 2] + ws_l[b*CHUNKS + 3];
    const float inv = 1.0f / L;

    float4* ap = reinterpret_cast<float4*>(out + NB*DKD + (size_t)b * NT + (size_t)c * TC);
    float4 p = ap[tid];
    p.x *= inv; p.y *= inv; p.z *= inv; p.w *= inv;
    ap[tid] = p;

    if (c == 0 && tid < DKD) {
        const float* wc = ws_ctx + b * CHUNKS * 16;
        out[b * DKD + tid] = (wc[tid] + wc[16 + tid] + wc[32 + tid] + wc[48 + tid]) * inv;
    }
}

extern "C" void kernel_launch(void* const* d_in, const int* in_sizes, int n_in,
                              void* d_out, int out_size, void* d_ws, size_t ws_size,
                              hipStream_t stream) {
    const float* query = (const float*)d_in[0];
    const float* key   = (const float*)d_in[1];
    const float* value = (const float*)d_in[2];
    const float* W1    = (const float*)d_in[3];
    const float* W2    = (const float*)d_in[4];
    const float* bias  = (const float*)d_in[5];
    const float* v_w   = (const float*)d_in[6];
    const float* v_b   = (const float*)d_in[7];
    float* out = (float*)d_out;

    float* ws_l   = (float*)d_ws;          // NB*CHUNKS floats
    float* ws_ctx = ws_l + NB * CHUNKS;    // NB*CHUNKS*16 floats

    aa_score<<<NB * CHUNKS, BLK, 0, stream>>>(
        query, key, value, W1, W2, bias, v_w, v_b,
        out + NB * DKD, ws_l, ws_ctx);
    aa_finish<<<NB * CHUNKS, BLK, 0, stream>>>(out, ws_l, ws_ctx);
}